// Round 1
// baseline (884.706 us; speedup 1.0000x reference)
//
#include <hip/hip_runtime.h>

#define NB 256            // blocks (1 per CU)
#define BT 512            // threads per block (8 waves)
#define MSTEPS 8
// Fixed problem shape: L = 500000.
#define CHUNK 1954        // ceil(500000 / NB) rows per block
#define REGT 13           // register-resident rows per quad (13*128 = 1664 rows)
#define REGL (REGT * 128)
#define LDSROWS (CHUNK - REGL)   // 290 rows resident in LDS
#define LDSTRIDE 36       // 36 floats = 144 B padded row -> 2-way (free) bank aliasing

struct PParams {
  const float* candidate;
  const float* z_past;
  const float* q_w; const float* q_b;
  const float* k_w; const float* k_b;
  const float* v_w; const float* v_b;
  const float* o_w; const float* o_b;
  const float* rel_bias;
  const float* coupling;
  const float* norm_scale;
  float* out;
  float* ws;   // [0..15] uint barrier state (memset to 0 each launch); [16..] 2*132*NB partials
  int L;
};

__device__ __forceinline__ float mish_f(float x) {
  float sp = fmaxf(x, 0.0f) + log1pf(expf(-fabsf(x)));
  return x * tanhf(sp);
}

// Recompute q projection, folded score vectors a_h (pre-scaled by inv_sqrt_d=0.5),
// and the l<64 relative-bias delta table, from the current state sZ.
// Must be called by ALL threads of the block (contains barriers).
__device__ void compute_qar(const PParams& p, int tid,
                            float* sZ, float* sQ, float* sA, float* sRel) {
  if (tid < 32) {
    float acc = p.q_b[tid];
    const float* row = p.q_w + tid * 32;
    #pragma unroll
    for (int c = 0; c < 32; ++c) acc = fmaf(row[c], sZ[c], acc);
    sQ[tid] = acc;
  }
  __syncthreads();
  if (tid < 128) {
    int h = tid >> 5, c = tid & 31;
    float acc = 0.f;
    #pragma unroll
    for (int jj = 0; jj < 8; ++jj)
      acc = fmaf(sQ[8 * h + jj], p.k_w[(8 * h + jj) * 32 + c], acc);
    sA[tid] = 0.5f * acc;               // fold inv_sqrt_d
  }
  if (tid >= 256) {
    // rel-bias delta vs the saturated idx=128 entry (constant part cancels in softmax)
    int t = tid - 256;
    int l = t >> 2, h = t & 3;
    float acc = 0.f;
    #pragma unroll
    for (int jj = 0; jj < 8; ++jj) {
      int jidx = 8 * h + jj;
      acc = fmaf(sQ[jidx],
                 p.rel_bias[(l + 64) * 32 + jidx] - p.rel_bias[128 * 32 + jidx],
                 acc);
    }
    sRel[t] = 0.5f * acc;
  }
  __syncthreads();
}

// Minimal grid barrier: one release-add per block, relaxed spin on a flag,
// agent fences at the edges. Counters zeroed by hipMemsetAsync each launch.
__device__ __forceinline__ void grid_barrier(float* wsf, int iter, int tid) {
  unsigned* sync = reinterpret_cast<unsigned*>(wsf);
  __syncthreads();
  __threadfence();                     // release block's partial-table stores (wbl2)
  if (tid == 0) {
    unsigned* cnt = sync + 2 * iter;
    unsigned* flg = sync + 2 * iter + 1;
    unsigned old = __hip_atomic_fetch_add(cnt, 1u, __ATOMIC_RELEASE,
                                          __HIP_MEMORY_SCOPE_AGENT);
    if (old == (unsigned)(NB - 1)) {
      __hip_atomic_store(flg, 1u, __ATOMIC_RELEASE, __HIP_MEMORY_SCOPE_AGENT);
    } else {
      while (__hip_atomic_load(flg, __ATOMIC_RELAXED,
                               __HIP_MEMORY_SCOPE_AGENT) == 0u)
        __builtin_amdgcn_s_sleep(4);   // ~256-cycle poll granularity
    }
  }
  __syncthreads();
  __threadfence();                     // acquire: invalidate stale L1/L2 before reads
}

// One l-row contribution: 32-wide dot split over the 4-lane quad, softmax weight, accumulate.
__device__ __forceinline__ void trip_body(const float (&A)[4][8], const float* sRel,
                                          const float* zv, bool dorel, int relrow,
                                          float (&S)[4][8], float (&Zc)[4]) {
  float d[4] = {0.f, 0.f, 0.f, 0.f};
  #pragma unroll
  for (int h = 0; h < 4; ++h)
    #pragma unroll
    for (int k = 0; k < 8; ++k) d[h] = fmaf(A[h][k], zv[k], d[h]);
  #pragma unroll
  for (int h = 0; h < 4; ++h) {
    d[h] += __shfl_xor(d[h], 1);
    d[h] += __shfl_xor(d[h], 2);
  }
  if (dorel) {
    const float4 r = reinterpret_cast<const float4*>(sRel)[relrow];
    d[0] += r.x; d[1] += r.y; d[2] += r.z; d[3] += r.w;
  }
  #pragma unroll
  for (int h = 0; h < 4; ++h) {
    float w = __expf(d[h]);
    Zc[h] += w;
    #pragma unroll
    for (int k = 0; k < 8; ++k) S[h][k] = fmaf(w, zv[k], S[h][k]);
  }
}

__global__ __launch_bounds__(BT, 2)
void photonic_kernel(PParams p) {
  __shared__ float sZ[32];
  __shared__ float sQ[32];
  __shared__ float sOutV[32];
  __shared__ float sZn[32];
  __shared__ __align__(16) float sA[128];     // a[h][c]
  __shared__ __align__(16) float sRel[256];   // relT[l][h], l<64
  __shared__ float sRed[BT / 64][4][36];      // per-wave reduced (S[4][8] + Z[4]) per quarter
  __shared__ float sSS[128];                  // global-reduced S[h][c]
  __shared__ float sSZ[4];                    // global-reduced Z[h]
  __shared__ __align__(16) float sZp[LDSROWS * LDSTRIDE];  // LDS-resident z rows (padded)

  const int tid  = threadIdx.x;
  const int b    = blockIdx.x;
  const int j    = tid & 3;        // quarter (owns columns [8j, 8j+8))
  const int quad = tid >> 2;       // 0..127
  const int wave = tid >> 6;
  const int lane = tid & 63;

  const int chunk0 = b * CHUNK;
  const int clen   = min(CHUNK, p.L - chunk0);          // 1954, last block 1730
  const int ldsl   = min(clen - REGL, (int)LDSROWS);    // 290, last block 66

  // init state z = candidate (real-interleaved flat 32)
  if (tid < 32) sZ[tid] = p.candidate[tid];
  __syncthreads();
  compute_qar(p, tid, sZ, sQ, sA, sRel);

  // Register-resident slice of z_past: rows chunk0 + quad + t*128, t < REGT.
  float zreg[REGT][8];

  for (int iter = 0; iter < MSTEPS; ++iter) {
    // stage my quarter of a[h][*] into registers
    float A[4][8];
    #pragma unroll
    for (int h = 0; h < 4; ++h)
      #pragma unroll
      for (int k = 0; k < 8; ++k)
        A[h][k] = sA[h * 32 + j * 8 + k];

    float S[4][8];
    #pragma unroll
    for (int h = 0; h < 4; ++h)
      #pragma unroll
      for (int k = 0; k < 8; ++k) S[h][k] = 0.f;
    float Zc[4] = {0.f, 0.f, 0.f, 0.f};

    if (iter == 0) {
      // ---- first pass: load from HBM, populate registers + LDS, and compute ----
      #pragma unroll
      for (int t = 0; t < REGT; ++t) {
        const float4* zr = reinterpret_cast<const float4*>(
            p.z_past + (size_t)(chunk0 + quad + (t << 7)) * 32) + (j * 2);
        float4 za = zr[0];
        float4 zb = zr[1];
        zreg[t][0] = za.x; zreg[t][1] = za.y; zreg[t][2] = za.z; zreg[t][3] = za.w;
        zreg[t][4] = zb.x; zreg[t][5] = zb.y; zreg[t][6] = zb.z; zreg[t][7] = zb.w;
        bool dorel = (b == 0) && (t == 0) && (quad < 64);
        trip_body(A, sRel, zreg[t], dorel, quad, S, Zc);
      }
      #pragma unroll
      for (int t = 0; t < 3; ++t) {
        int li = quad + (t << 7);
        if (li < ldsl) {
          const float4* zr = reinterpret_cast<const float4*>(
              p.z_past + (size_t)(chunk0 + REGL + li) * 32) + (j * 2);
          float4 za = zr[0];
          float4 zb = zr[1];
          float4* dst = reinterpret_cast<float4*>(sZp + li * LDSTRIDE + j * 8);
          dst[0] = za;
          dst[1] = zb;
          float zv[8] = {za.x, za.y, za.z, za.w, zb.x, zb.y, zb.z, zb.w};
          trip_body(A, sRel, zv, false, 0, S, Zc);
        }
      }
    } else {
      // ---- steady state: zero global traffic; registers + LDS only ----
      #pragma unroll
      for (int t = 0; t < REGT; ++t) {
        bool dorel = (b == 0) && (t == 0) && (quad < 64);
        trip_body(A, sRel, zreg[t], dorel, quad, S, Zc);
      }
      #pragma unroll
      for (int t = 0; t < 3; ++t) {
        int li = quad + (t << 7);
        if (li < ldsl) {
          const float4* src = reinterpret_cast<const float4*>(sZp + li * LDSTRIDE + j * 8);
          float4 za = src[0];
          float4 zb = src[1];
          float zv[8] = {za.x, za.y, za.z, za.w, zb.x, zb.y, zb.z, zb.w};
          trip_body(A, sRel, zv, false, 0, S, Zc);
        }
      }
    }

    // reduce across the 16 quads of each wave (lane%4 == quarter is preserved)
    #pragma unroll
    for (int m = 4; m <= 32; m <<= 1) {
      #pragma unroll
      for (int h = 0; h < 4; ++h) {
        #pragma unroll
        for (int k = 0; k < 8; ++k) S[h][k] += __shfl_xor(S[h][k], m);
        Zc[h] += __shfl_xor(Zc[h], m);
      }
    }
    if ((lane >> 2) == 0) {  // lanes 0..3: lane == quarter j
      #pragma unroll
      for (int h = 0; h < 4; ++h) {
        #pragma unroll
        for (int k = 0; k < 8; ++k) sRed[wave][lane][h * 8 + k] = S[h][k];
        sRed[wave][lane][32 + h] = Zc[h];
      }
    }
    __syncthreads();

    // per-block partials -> global, component-major [comp][block] for coalesced reduce
    float* part = p.ws + 16 + (iter & 1) * (132 * NB);
    if (tid < 132) {
      float acc = 0.f;
      if (tid < 128) {
        int h = tid >> 5, c = tid & 31;
        int jj = c >> 3, k = c & 7;
        #pragma unroll
        for (int w2 = 0; w2 < BT / 64; ++w2) acc += sRed[w2][jj][h * 8 + k];
        part[(h * 33 + c) * NB + b] = acc;
      } else {
        int h = tid - 128;
        #pragma unroll
        for (int w2 = 0; w2 < BT / 64; ++w2) acc += sRed[w2][0][32 + h];
        part[(h * 33 + 32) * NB + b] = acc;
      }
    }

    grid_barrier(p.ws, iter, tid);

    // every block redundantly reduces all partials (135 KB, L2/L3-resident)
    if (tid < 132) {
      const float4* pp = reinterpret_cast<const float4*>(part + tid * NB);
      float acc = 0.f;
      for (int i = 0; i < NB / 4; ++i) {
        float4 v4 = pp[i];
        acc += (v4.x + v4.y) + (v4.z + v4.w);
      }
      int h = tid / 33, k = tid % 33;
      if (k < 32) sSS[h * 32 + k] = acc; else sSZ[h] = acc;
    }
    __syncthreads();

    // out_flat[j'] = v_w[j',:] @ (S_h / Z_h) + v_b[j']   (h = j'>>3)
    if (tid < 32) {
      int h = tid >> 3;
      float acc = 0.f;
      const float* row = p.v_w + tid * 32;
      #pragma unroll
      for (int c = 0; c < 32; ++c) acc = fmaf(row[c], sSS[h * 32 + c], acc);
      sOutV[tid] = acc / sSZ[h] + p.v_b[tid];
    }
    __syncthreads();
    // mod = o_w @ out + o_b ; z += coupling*mod ; mish
    if (tid < 32) {
      float acc = p.o_b[tid];
      const float* row = p.o_w + tid * 32;
      #pragma unroll
      for (int c = 0; c < 32; ++c) acc = fmaf(row[c], sOutV[c], acc);
      float zv2 = sZ[tid] + p.coupling[0] * acc;
      sZn[tid] = mish_f(zv2);
    }
    __syncthreads();
    // layer-norm over the 16 real / 16 imag components separately
    if (tid < 32) {
      int par = tid & 1;
      float m = 0.f;
      #pragma unroll
      for (int e = 0; e < 16; ++e) m += sZn[2 * e + par];
      m *= (1.f / 16.f);
      float v = 0.f;
      #pragma unroll
      for (int e = 0; e < 16; ++e) { float dd = sZn[2 * e + par] - m; v = fmaf(dd, dd, v); }
      v *= (1.f / 16.f);
      sZ[tid] = (sZn[tid] - m) * rsqrtf(v + 1e-5f) * p.norm_scale[0];
    }
    __syncthreads();

    if (iter != MSTEPS - 1) {
      compute_qar(p, tid, sZ, sQ, sA, sRel);
    } else {
      if (b == 0 && tid < 32) p.out[tid] = sZ[tid];
    }
  }
}

extern "C" void kernel_launch(void* const* d_in, const int* in_sizes, int n_in,
                              void* d_out, int out_size, void* d_ws, size_t ws_size,
                              hipStream_t stream) {
  PParams p;
  p.candidate  = (const float*)d_in[0];
  p.z_past     = (const float*)d_in[1];
  p.q_w = (const float*)d_in[2];  p.q_b = (const float*)d_in[3];
  p.k_w = (const float*)d_in[4];  p.k_b = (const float*)d_in[5];
  p.v_w = (const float*)d_in[6];  p.v_b = (const float*)d_in[7];
  p.o_w = (const float*)d_in[8];  p.o_b = (const float*)d_in[9];
  p.rel_bias   = (const float*)d_in[10];
  p.coupling   = (const float*)d_in[11];
  p.norm_scale = (const float*)d_in[12];
  p.out = (float*)d_out;
  p.ws  = (float*)d_ws;
  p.L   = in_sizes[1] / 32;

  // zero the 16 barrier words (captured as a graph node -> re-zeroed every replay)
  hipMemsetAsync(d_ws, 0, 64, stream);

  void* args[] = { &p };
  hipLaunchCooperativeKernel((const void*)photonic_kernel,
                             dim3(NB), dim3(BT), args, 0, stream);
}